// Round 1
// 1440.337 us; speedup vs baseline: 1.0636x; 1.0636x over previous
//
#include <hip/hip_runtime.h>
#include <hip/hip_bf16.h>

// Problem constants
#define NS 1280
#define NQ 65536
#define NA (NS + NQ)          // 66816 = 261*256
#define DIN 2048
#define DEMB 1024
#define NC 64
#define STEPS 5
#define NDBLK (NQ / 128)      // 512 dist blocks

typedef __attribute__((ext_vector_type(8))) __bf16 bf16x8;
typedef __attribute__((ext_vector_type(4))) float f32x4;
typedef unsigned short u16;

__device__ __forceinline__ float b2f(u16 u) {
  return __uint_as_float(((unsigned int)u) << 16);
}
__device__ __forceinline__ u16 f2b(float f) {
  __hip_bfloat16 h = __float2bfloat16(f);
  u16 u; __builtin_memcpy(&u, &h, 2); return u;
}
__device__ __forceinline__ void gld_lds16(const void* g, void* l) {
  __builtin_amdgcn_global_load_lds(
      (const __attribute__((address_space(1))) void*)g,
      (__attribute__((address_space(3))) void*)l, 16, 0, 0);
}

// ---------------- f32 -> bf16 convert (vectorized) ----------------
__global__ __launch_bounds__(256) void cvt_bf16(const float4* __restrict__ in,
                                                ushort4* __restrict__ out, int n4) {
  for (int i = blockIdx.x * 256 + threadIdx.x; i < n4; i += gridDim.x * 256) {
    float4 v = in[i];
    ushort4 o;
    o.x = f2b(v.x); o.y = f2b(v.y); o.z = f2b(v.z); o.w = f2b(v.w);
    out[i] = o;
  }
}

// ---------------- W [2048][1024] f32 -> Wt [1024][2048] bf16 ----------------
__global__ __launch_bounds__(256) void transpose_w(const float* __restrict__ W,
                                                   u16* __restrict__ Wt) {
  __shared__ float tile[32][33];
  const int bx = blockIdx.x;  // n-tile (0..31)
  const int by = blockIdx.y;  // k-tile (0..63)
  const int tx = threadIdx.x & 31, ty = threadIdx.x >> 5;  // ty 0..7
#pragma unroll
  for (int j = 0; j < 4; j++)
    tile[ty + 8 * j][tx] = W[(size_t)(by * 32 + ty + 8 * j) * DEMB + bx * 32 + tx];
  __syncthreads();
#pragma unroll
  for (int j = 0; j < 4; j++)
    Wt[(size_t)(bx * 32 + ty + 8 * j) * DIN + by * 32 + tx] = f2b(tile[tx][ty + 8 * j]);
}

// ---------------- 16-MFMA quadrant helper ----------------
__device__ __forceinline__ void mm16(const bf16x8 af[4], const bf16x8 bf[4],
                                     f32x4 (&acc)[4][4]) {
#pragma unroll
  for (int mt = 0; mt < 4; ++mt)
#pragma unroll
    for (int nt = 0; nt < 4; ++nt)
      acc[mt][nt] = __builtin_amdgcn_mfma_f32_16x16x32_bf16(af[mt], bf[nt],
                                                            acc[mt][nt], 0, 0, 0);
}

// ---------------- encoder GEMM: emb[NA][1024] = A[NA][2048] @ Wt[1024][2048]^T + b ---
// 256x256 tile, BK=64, 8 waves (2Mx4N), 128 KiB LDS dbuf, 8-phase/2-K-tile schedule:
//   per phase: {ds_read frags || issue 1 half-tile gld_lds -> s_barrier ->
//               setprio(1) 16xMFMA setprio(0) -> s_barrier}
// counted vmcnt(2) ONCE per K-tile (never 0 in steady state):
//   S(t) = [A-h0,A-h1,B-h0,B-h1] issued during tile t-1 phases 0..3;
//   tile t phase 0 issues A-h0(t+1) then waits vmcnt(2) -> S(t) complete, 1 stage flying.
// LDS swizzle (both-sides, rule 21): linear gld_lds dest + pre-swizzled GLOBAL source
//   (chunk ^= row&7) + same XOR on ds_read (col16 ^= (lr&7)<<3) -> 2-way banks (free).
// XCD swizzle: HW maps block b -> XCD b%8; n-fast within XCD keeps A-tile L2-hot.
__global__ __launch_bounds__(512, 2) void encoder_gemm(const u16* __restrict__ A,
                                                       const u16* __restrict__ Bt,
                                                       const float* __restrict__ bias,
                                                       u16* __restrict__ C) {
  const int b = blockIdx.x;
  const int x = b & 7, tt = b >> 3;
  const int mblk = x + 8 * (tt >> 2);   // XCD x owns mblks with mblk%8 == x
  const int nblk = tt & 3;              // n-fast within XCD -> A-tile reuse
  if (mblk >= NA / 256) return;         // 261 m-tiles; up to 3 slots idle

  __shared__ u16 lds[65536];            // 128 KiB: [buf][A|B][256*64]

  const int m0 = mblk * 256, n0 = nblk * 256;
  const int t = threadIdx.x;
  const int w = t >> 6, l = t & 63;
  const int wm = (w >> 2) * 128;        // 0 or 128
  const int wn = (w & 3) * 64;          // 0,64,128,192
  const int lr = l & 15, lk8 = (l >> 4) * 8;
  const int swz = (lr & 7) << 3;        // read-side XOR (u16 units)

  // staging map: chunk c in 0..1023 covers one 128x64 half (16 KB); thread does c=t, t+512
  // lds dest (linear, lane-contiguous): c*16 bytes; global col chunk pre-swizzled by row&7
  const int c1 = t + 512;
  const int r0 = t >> 3, r1 = c1 >> 3;          // row within half
  const int sc0 = (((t & 7) ^ (r0 & 7)) << 3);  // swizzled col offset (u16)
  const int sc1 = (((c1 & 7) ^ (r1 & 7)) << 3);

  const u16* gAt = A + (size_t)m0 * DIN;
  const u16* gBt = Bt + (size_t)n0 * DIN;

  f32x4 acc[2][4][4];
  f32x4 z; z.x = 0.f; z.y = 0.f; z.z = 0.f; z.w = 0.f;
#pragma unroll
  for (int g = 0; g < 2; ++g)
#pragma unroll
    for (int i = 0; i < 4; ++i)
#pragma unroll
      for (int j = 0; j < 4; ++j) acc[g][i][j] = z;

  auto STAGE = [&](const u16* g, u16* S, int h, int kb) {
    gld_lds16(g + (size_t)(h * 128 + r0) * DIN + kb + sc0, S + h * 8192 + t * 8);
    gld_lds16(g + (size_t)(h * 128 + r1) * DIN + kb + sc1, S + h * 8192 + c1 * 8);
  };

  // prologue: stage K-tile 0 into buf0 (8 loads)
  STAGE(gAt, lds, 0, 0);
  STAGE(gAt, lds, 1, 0);
  STAGE(gBt, lds + 16384, 0, 0);
  STAGE(gBt, lds + 16384, 1, 0);

  const int NT = DIN / 64;  // 32
  for (int tk = 0; tk < NT; ++tk) {
    const int p = tk & 1;
    u16* LA = lds + p * 32768;
    u16* LB = LA + 16384;
    u16* SA = lds + (p ^ 1) * 32768;
    u16* SB = SA + 16384;
    const int kbn = (tk + 1) * 64;
    const bool pre = (tk + 1 < NT);

    bf16x8 af[4], bf0[4], bf1[4];

    // ---- phase 0: (mg0, kk0); stage A-h0(t+1); tile-boundary counted wait ----
    if (pre) {
      STAGE(gAt, SA, 0, kbn);
      asm volatile("s_waitcnt vmcnt(2)" ::: "memory");
    } else {
      asm volatile("s_waitcnt vmcnt(0)" ::: "memory");
    }
    __builtin_amdgcn_s_barrier();
#pragma unroll
    for (int mt = 0; mt < 4; ++mt)
      af[mt] = *(const bf16x8*)&LA[(wm + mt * 16 + lr) * 64 + (lk8 ^ swz)];
#pragma unroll
    for (int nt = 0; nt < 4; ++nt)
      bf0[nt] = *(const bf16x8*)&LB[(wn + nt * 16 + lr) * 64 + (lk8 ^ swz)];
    __builtin_amdgcn_s_setprio(1);
    mm16(af, bf0, acc[0]);
    __builtin_amdgcn_s_setprio(0);
    __builtin_amdgcn_s_barrier();

    // ---- phase 1: (mg1, kk0); stage A-h1(t+1) ----
#pragma unroll
    for (int mt = 0; mt < 4; ++mt)
      af[mt] = *(const bf16x8*)&LA[(wm + 64 + mt * 16 + lr) * 64 + (lk8 ^ swz)];
    if (pre) STAGE(gAt, SA, 1, kbn);
    __builtin_amdgcn_s_barrier();
    __builtin_amdgcn_s_setprio(1);
    mm16(af, bf0, acc[1]);
    __builtin_amdgcn_s_setprio(0);
    __builtin_amdgcn_s_barrier();

    // ---- phase 2: (mg0, kk1); stage B-h0(t+1) ----
#pragma unroll
    for (int mt = 0; mt < 4; ++mt)
      af[mt] = *(const bf16x8*)&LA[(wm + mt * 16 + lr) * 64 + ((32 + lk8) ^ swz)];
#pragma unroll
    for (int nt = 0; nt < 4; ++nt)
      bf1[nt] = *(const bf16x8*)&LB[(wn + nt * 16 + lr) * 64 + ((32 + lk8) ^ swz)];
    if (pre) STAGE(gBt, SB, 0, kbn);
    __builtin_amdgcn_s_barrier();
    __builtin_amdgcn_s_setprio(1);
    mm16(af, bf1, acc[0]);
    __builtin_amdgcn_s_setprio(0);
    __builtin_amdgcn_s_barrier();

    // ---- phase 3: (mg1, kk1); stage B-h1(t+1) ----
#pragma unroll
    for (int mt = 0; mt < 4; ++mt)
      af[mt] = *(const bf16x8*)&LA[(wm + 64 + mt * 16 + lr) * 64 + ((32 + lk8) ^ swz)];
    if (pre) STAGE(gBt, SB, 1, kbn);
    __builtin_amdgcn_s_barrier();
    __builtin_amdgcn_s_setprio(1);
    mm16(af, bf1, acc[1]);
    __builtin_amdgcn_s_setprio(0);
    __builtin_amdgcn_s_barrier();
  }

  // epilogue: C layout col=lane&15, row=(lane>>4)*4+reg  [m89/m91 verified]
  float bv[4];
#pragma unroll
  for (int nt = 0; nt < 4; ++nt) bv[nt] = bias[n0 + wn + nt * 16 + lr];
#pragma unroll
  for (int mg = 0; mg < 2; ++mg)
#pragma unroll
    for (int mt = 0; mt < 4; ++mt)
#pragma unroll
      for (int nt = 0; nt < 4; ++nt)
#pragma unroll
        for (int r = 0; r < 4; ++r) {
          int row = m0 + wm + mg * 64 + mt * 16 + (l >> 4) * 4 + r;
          int col = n0 + wn + nt * 16 + lr;
          C[(size_t)row * DEMB + col] = f2b(acc[mg][mt][nt][r] + bv[nt]);
        }
}

// ---------------- support class sums (loop-invariant) ----------------
__global__ __launch_bounds__(256) void support_sums(const u16* __restrict__ emb,
                                                    const int* __restrict__ slab,
                                                    float* __restrict__ ssum,
                                                    int* __restrict__ scount) {
  const int c = blockIdx.x, t = threadIdx.x;
  __shared__ int lab[NS];
  for (int i = t; i < NS; i += 256) lab[i] = slab[i];
  __syncthreads();
  float a0 = 0, a1 = 0, a2 = 0, a3 = 0;
  int cnt = 0;
  for (int i = 0; i < NS; i++) {
    if (lab[i] == c) {
      ushort4 e = *(const ushort4*)&emb[(size_t)i * DEMB + t * 4];
      a0 += b2f(e.x); a1 += b2f(e.y); a2 += b2f(e.z); a3 += b2f(e.w);
      cnt++;
    }
  }
  float* dst = ssum + (size_t)c * DEMB + t * 4;
  dst[0] = a0; dst[1] = a1; dst[2] = a2; dst[3] = a3;
  if (t == 0) scount[c] = cnt;
}

// ---------------- |q|^2 per query row ----------------
__global__ __launch_bounds__(256) void qnorm_kernel(const u16* __restrict__ Q,
                                                    float* __restrict__ qnorm) {
  const int t = threadIdx.x, w = t >> 6, l = t & 63;
  const int row = blockIdx.x * 4 + w;
  const u16* p = Q + (size_t)row * DEMB;
  float s = 0.f;
#pragma unroll
  for (int kk = 0; kk < 4; kk++) {
    ushort4 e = *(const ushort4*)&p[kk * 256 + l * 4];
    float x0 = b2f(e.x), x1 = b2f(e.y), x2 = b2f(e.z), x3 = b2f(e.w);
    s += x0 * x0 + x1 * x1 + x2 * x2 + x3 * x3;
  }
#pragma unroll
  for (int d = 32; d >= 1; d >>= 1) s += __shfl_xor(s, d);
  if (l == 0) qnorm[row] = s;
}

// ---------------- prototype finalize: (ssum + sum(qpart))/max(cnt,1) -> bf16, |p|^2 --
template <bool INIT>
__global__ __launch_bounds__(256) void finalize_protos(const float* __restrict__ ssum,
                                                       const int* __restrict__ scount,
                                                       const float* __restrict__ qpart,
                                                       const int* __restrict__ histpart,
                                                       u16* __restrict__ protos,
                                                       float* __restrict__ pnorm) {
  const int c = blockIdx.x, t = threadIdx.x;
  __shared__ int wredi[4];
  __shared__ float wredf[4];
  __shared__ int cnt_sh;
  float inv;
  if (INIT) {
    inv = 1.0f / fmaxf((float)scount[c], 1.0f);
  } else {
    int p = histpart[(size_t)c * NDBLK + t] + histpart[(size_t)c * NDBLK + 256 + t];
#pragma unroll
    for (int d = 32; d >= 1; d >>= 1) p += __shfl_xor(p, d);
    if ((t & 63) == 0) wredi[t >> 6] = p;
    __syncthreads();
    if (t == 0) cnt_sh = scount[c] + wredi[0] + wredi[1] + wredi[2] + wredi[3];
    __syncthreads();
    inv = 1.0f / fmaxf((float)cnt_sh, 1.0f);
  }
  float part = 0.f;
#pragma unroll
  for (int j = 0; j < 4; j++) {
    const int d = t * 4 + j;
    float v = ssum[(size_t)c * DEMB + d];
    if (!INIT) {
#pragma unroll
      for (int ch = 0; ch < 8; ch++)
        v += qpart[((size_t)ch * NC + c) * DEMB + d];
    }
    v *= inv;
    u16 bits = f2b(v);
    protos[(size_t)c * DEMB + d] = bits;
    float vb = b2f(bits);  // norm on the rounded value = what the MFMA dot sees
    part += vb * vb;
  }
#pragma unroll
  for (int d = 32; d >= 1; d >>= 1) part += __shfl_xor(part, d);
  if ((t & 63) == 0) wredf[t >> 6] = part;
  __syncthreads();
  if (t == 0) pnorm[c] = wredf[0] + wredf[1] + wredf[2] + wredf[3];
}

// ---------------- distance kernel: MODE 0 = argmin labels+hist, MODE 1 = logits ----
template <int MODE>
__global__ __launch_bounds__(256) void dist_kernel(const u16* __restrict__ Q,
                                                   const u16* __restrict__ P,
                                                   const float* __restrict__ pnorm,
                                                   const float* __restrict__ qnorm,
                                                   int* __restrict__ labels,
                                                   int* __restrict__ histpart,
                                                   float* __restrict__ out) {
  __shared__ u16 As[128 * 32];
  __shared__ u16 Bs[64 * 32];
  __shared__ int hist[NC];
  const int t = threadIdx.x;
  if (MODE == 0 && t < NC) hist[t] = 0;
  const int m0 = blockIdx.x * 128;
  const int w = t >> 6, l = t & 63;
  const int lr = l & 15, lk = (l >> 4) * 8;
  const int wm = w * 32;

  f32x4 acc[2][4];
  f32x4 z; z.x = 0.f; z.y = 0.f; z.z = 0.f; z.w = 0.f;
#pragma unroll
  for (int i = 0; i < 2; i++)
#pragma unroll
    for (int j = 0; j < 4; j++) acc[i][j] = z;

  const int rA0 = t >> 2, k8 = (t & 3) * 8;
  const u16* gA = Q + (size_t)(m0 + rA0) * DEMB + k8;
  const u16* gB = P + (size_t)rA0 * DEMB + k8;  // rA0 in 0..63 covers all protos
  u16* lA = As + t * 8;
  u16* lB = Bs + t * 8;

  for (int kb = 0; kb < DEMB; kb += 32) {
    gld_lds16(gA + kb, lA);
    gld_lds16(gA + kb + (size_t)64 * DEMB, lA + 64 * 32);
    gld_lds16(gB + kb, lB);
    __syncthreads();
    bf16x8 af[2], bf[4];
#pragma unroll
    for (int mt = 0; mt < 2; mt++) af[mt] = *(const bf16x8*)&As[(wm + mt * 16 + lr) * 32 + lk];
#pragma unroll
    for (int nt = 0; nt < 4; nt++) bf[nt] = *(const bf16x8*)&Bs[(nt * 16 + lr) * 32 + lk];
#pragma unroll
    for (int mt = 0; mt < 2; mt++)
#pragma unroll
      for (int nt = 0; nt < 4; nt++)
        acc[mt][nt] = __builtin_amdgcn_mfma_f32_16x16x32_bf16(af[mt], bf[nt], acc[mt][nt], 0, 0, 0);
    __syncthreads();
  }

  if (MODE == 0) {
    // argmin_c (|p_c|^2 - 2 q.p_c); |q|^2 invariant to argmin
#pragma unroll
    for (int mt = 0; mt < 2; mt++)
#pragma unroll
      for (int r = 0; r < 4; r++) {
        float best = 3.402e38f; int bc = 0;
#pragma unroll
        for (int nt = 0; nt < 4; nt++) {
          int col = nt * 16 + lr;
          float v = pnorm[col] - 2.0f * acc[mt][nt][r];
          if (v < best) { best = v; bc = col; }  // cols ascend -> first-min tie-break
        }
#pragma unroll
        for (int s = 1; s < 16; s <<= 1) {
          float ov = __shfl_xor(best, s);
          int oc = __shfl_xor(bc, s);
          if (ov < best || (ov == best && oc < bc)) { best = ov; bc = oc; }
        }
        if (lr == 0) {
          int row = m0 + wm + mt * 16 + (l >> 4) * 4 + r;
          labels[row] = bc;
          atomicAdd(&hist[bc], 1);  // LDS atomic only
        }
      }
    __syncthreads();
    if (t < NC) histpart[(size_t)t * NDBLK + blockIdx.x] = hist[t];
  } else {
#pragma unroll
    for (int mt = 0; mt < 2; mt++)
#pragma unroll
      for (int nt = 0; nt < 4; nt++)
#pragma unroll
        for (int r = 0; r < 4; r++) {
          int row = m0 + wm + mt * 16 + (l >> 4) * 4 + r;
          int col = nt * 16 + lr;
          float d2 = qnorm[row] + pnorm[col] - 2.0f * acc[mt][nt][r];
          out[(size_t)row * NC + col] = -sqrtf(fmaxf(d2, 1e-12f));
        }
  }
}

// ---------------- per-class gather sum (sort-free segment_sum, partials) ----------
__global__ __launch_bounds__(256) void class_gather_sum(const u16* __restrict__ Q,
                                                        const int* __restrict__ labels,
                                                        float* __restrict__ qpart) {
  const int c = blockIdx.x >> 3;
  const int chunk = blockIdx.x & 7;
  const int base = chunk * (NQ / 8);  // 8192 rows per chunk
  const int t = threadIdx.x;
  __shared__ int list[NQ / 8];
  __shared__ int nmatch;
  if (t == 0) nmatch = 0;
  __syncthreads();
  for (int i = t; i < NQ / 8; i += 256) {
    if (labels[base + i] == c) {
      int p = atomicAdd(&nmatch, 1);
      list[p] = base + i;
    }
  }
  __syncthreads();
  const int cnt = nmatch;
  float a0 = 0, a1 = 0, a2 = 0, a3 = 0;
  for (int j = 0; j < cnt; j++) {
    int row = list[j];
    ushort4 e = *(const ushort4*)&Q[(size_t)row * DEMB + t * 4];
    a0 += b2f(e.x); a1 += b2f(e.y); a2 += b2f(e.z); a3 += b2f(e.w);
  }
  // always write (zeros included) -> no memset needed
  float* dst = qpart + ((size_t)chunk * NC + c) * DEMB + t * 4;
  dst[0] = a0; dst[1] = a1; dst[2] = a2; dst[3] = a3;
}

extern "C" void kernel_launch(void* const* d_in, const int* in_sizes, int n_in,
                              void* d_out, int out_size, void* d_ws, size_t ws_size,
                              hipStream_t stream) {
  const float* support = (const float*)d_in[0];   // [1280][2048]
  const float* query   = (const float*)d_in[1];   // [65536][2048]
  const int*   slab    = (const int*)d_in[2];     // [1280]
  const float* W       = (const float*)d_in[3];   // [2048][1024]
  const float* bias    = (const float*)d_in[4];   // [1024]
  float* out = (float*)d_out;                     // [65536][64]

  // ---- workspace carve-up (~416 MB) ----
  u16* Abf = (u16*)d_ws;                               // [NA][DIN] bf16 (dead after encoder)
  u16* Wt  = Abf + (size_t)NA * DIN;                   // [DEMB][DIN] bf16
  u16* emb = Wt + (size_t)DEMB * DIN;                  // [NA][DEMB] bf16
  float* ssum  = (float*)(emb + (size_t)NA * DEMB);    // [64][1024]
  float* pnorm = ssum + (size_t)NC * DEMB;             // [64]
  float* qnorm = pnorm + NC;                           // [65536]
  int* scount  = (int*)(qnorm + NQ);                   // [64]
  int* labels  = scount + NC;                          // [65536]
  u16* protos  = (u16*)(labels + NQ);                  // [64][1024] bf16
  // alias partial buffers into Abf (only used after encoder_gemm is done)
  float* qpart = (float*)Abf;                          // [8][64][1024] f32 = 2 MB
  int* histpart = (int*)(qpart + (size_t)8 * NC * DEMB); // [64][512] = 128 KB

  const u16* Qemb = emb + (size_t)NS * DEMB;

  // 1) convert inputs to bf16
  cvt_bf16<<<2048, 256, 0, stream>>>((const float4*)support, (ushort4*)Abf,
                                     NS * DIN / 4);
  cvt_bf16<<<8192, 256, 0, stream>>>((const float4*)query,
                                     (ushort4*)(Abf + (size_t)NS * DIN),
                                     NQ * DIN / 4);
  transpose_w<<<dim3(32, 64), 256, 0, stream>>>(W, Wt);

  // 2) encoder GEMM -> emb (256^2 8-phase; XCD-swizzled grid: 8 slots * 33 m-groups * 4 n)
  encoder_gemm<<<8 * 33 * 4, 512, 0, stream>>>(Abf, Wt, bias, emb);

  // 3) loop-invariant pieces
  support_sums<<<NC, 256, 0, stream>>>(emb, slab, ssum, scount);
  qnorm_kernel<<<NQ / 4, 256, 0, stream>>>(Qemb, qnorm);

  // 4) initial prototypes: support only (no memsets needed)
  finalize_protos<true><<<NC, 256, 0, stream>>>(ssum, scount, qpart, histpart,
                                                protos, pnorm);

  // 5) transductive refinement (3 dispatches/iter, no memsets, no global atomics)
  for (int it = 0; it < STEPS; ++it) {
    dist_kernel<0><<<NDBLK, 256, 0, stream>>>(Qemb, protos, pnorm, nullptr,
                                              labels, histpart, nullptr);
    class_gather_sum<<<NC * 8, 256, 0, stream>>>(Qemb, labels, qpart);
    finalize_protos<false><<<NC, 256, 0, stream>>>(ssum, scount, qpart, histpart,
                                                   protos, pnorm);
  }

  // 6) final logits
  dist_kernel<1><<<NDBLK, 256, 0, stream>>>(Qemb, protos, pnorm, qnorm,
                                            nullptr, nullptr, out);
}